// Round 7
// baseline (2618.574 us; speedup 1.0000x reference)
//
#include <hip/hip_runtime.h>

#define DI __device__ __forceinline__

typedef __bf16 bf16x8 __attribute__((ext_vector_type(8)));
typedef float  f32x4  __attribute__((ext_vector_type(4)));

DI unsigned short f2bf(float f){
  unsigned u = __builtin_bit_cast(unsigned, f);
  u = (u + 0x7fffu + ((u >> 16) & 1u)) >> 16;   // RNE
  return (unsigned short)u;
}
DI float b2f(unsigned short h){
  return __builtin_bit_cast(float, (unsigned)h << 16);
}
DI f32x4 MFMA(bf16x8 a, bf16x8 b, f32x4 c){
  return __builtin_amdgcn_mfma_f32_16x16x32_bf16(a, b, c, 0, 0, 0);
}
DI void gll16(const void* g, void* l){
  __builtin_amdgcn_global_load_lds((const __attribute__((address_space(1))) void*)g,
                                   (__attribute__((address_space(3))) void*)l,
                                   16, 0, 0);
}

// ---------------- elementwise / prep kernels ----------------

__global__ void k_f2b(const float* __restrict__ in, unsigned short* __restrict__ out, long n){
  long i = ((long)blockIdx.x*256 + threadIdx.x)*4;
  if (i >= n) return;
  float4 v = *(const float4*)(in + i);
  ushort4 r; r.x=f2bf(v.x); r.y=f2bf(v.y); r.z=f2bf(v.z); r.w=f2bf(v.w);
  *(ushort4*)(out + i) = r;
}

// wkv_a (576,2048) f32 -> (640,2048) bf16, pad rows zero
__global__ void k_wkva(const float* __restrict__ in, unsigned short* __restrict__ out){
  int idx = blockIdx.x*256 + threadIdx.x;         // 1280*256 = 640*2048/4
  long i = (long)idx*4;
  int row = (int)(i >> 11), col = (int)(i & 2047);
  ushort4 r;
  if (row < 576){
    float4 v = *(const float4*)(in + (long)row*2048 + col);
    r.x=f2bf(v.x); r.y=f2bf(v.y); r.z=f2bf(v.z); r.w=f2bf(v.w);
  } else { r.x=0; r.y=0; r.z=0; r.w=0; }
  *(ushort4*)(out + i) = r;
}

// wbkT[h][c][d] = wkv_b[(h*256 + d)*512 + c], d<128   (16,512,128) bf16
__global__ void k_wbkT(const float* __restrict__ wkvb, unsigned short* __restrict__ out){
  int i = blockIdx.x*256 + threadIdx.x;           // 4096*256 = 16*512*128
  int d = i & 127, c = (i>>7)&511, h = i>>16;
  out[i] = f2bf(wkvb[(long)((h<<8) + d)*512 + c]);
}

// rope q_pe: q_bf (4096,3072) -> qkcat cols 512..575
__global__ void k_ropeq(const unsigned short* __restrict__ q, const float* __restrict__ fc,
                        const float* __restrict__ fs, unsigned short* __restrict__ qkcat){
  int i = blockIdx.x*256 + threadIdx.x;           // 8192*256 = 4096*16*32
  int p = i & 31, h = (i>>5)&15, m = i>>9;
  int s = m & 2047;
  const unsigned short* qp = q + (long)m*3072 + h*192 + 128 + (p<<1);
  float xr = b2f(qp[0]), xi = b2f(qp[1]);
  float c = fc[(s<<5)+p], sn = fs[(s<<5)+p];
  unsigned short* dst = qkcat + ((long)m*16 + h)*576 + 512 + (p<<1);
  dst[0] = f2bf(xr*c - xi*sn);
  dst[1] = f2bf(xr*sn + xi*c);
}

// rope k_pe: kv_bf (4096,640) cols 512..575 -> kvcat cols 512..575
__global__ void k_ropek(const unsigned short* __restrict__ kv, const float* __restrict__ fc,
                        const float* __restrict__ fs, unsigned short* __restrict__ kvcat){
  int i = blockIdx.x*256 + threadIdx.x;           // 512*256 = 4096*32
  int p = i & 31, m = i>>5;
  int s = m & 2047;
  const unsigned short* kp = kv + (long)m*640 + 512 + (p<<1);
  float xr = b2f(kp[0]), xi = b2f(kp[1]);
  float c = fc[(s<<5)+p], sn = fs[(s<<5)+p];
  unsigned short* dst = kvcat + (long)m*576 + 512 + (p<<1);
  dst[0] = f2bf(xr*c - xi*sn);
  dst[1] = f2bf(xr*sn + xi*c);
}

// RMSNorm kv_c rows of 512 -> kvcat cols 0..511 (one wave per row)
__global__ __launch_bounds__(256)
void k_kvnorm(const unsigned short* __restrict__ kv, const float* __restrict__ w,
              unsigned short* __restrict__ kvcat){
  int m = blockIdx.x*4 + (threadIdx.x>>6);
  int l = threadIdx.x & 63;
  const unsigned short* row = kv + (long)m*640 + (l<<3);
  float v[8]; float ss = 0.f;
  #pragma unroll
  for (int j=0;j<8;j++){ v[j] = b2f(row[j]); ss += v[j]*v[j]; }
  #pragma unroll
  for (int d=1; d<64; d<<=1) ss += __shfl_xor(ss, d, 64);
  float r = rsqrtf(ss*(1.f/512.f) + 1.1920929e-07f);
  unsigned short* dst = kvcat + (long)m*576 + (l<<3);
  const float* wp = w + (l<<3);
  #pragma unroll
  for (int j=0;j<8;j++) dst[j] = f2bf(v[j]*r*wp[j]);
}

// vt[b][c][t] = kvcat[(b*2048+t)*576 + c]   (2,512,2048) bf16
__global__ void k_vt(const unsigned short* __restrict__ kvcat, unsigned short* __restrict__ vt){
  int i = blockIdx.x*256 + threadIdx.x;           // 8192*256 = 2*512*2048
  int t = i & 2047, c = (i>>11)&511, b = i>>20;
  vt[i] = kvcat[(long)((b<<11)+t)*576 + c];
}

// ---------------- GEMM: C(MxN) = A(MxK) * B(NxK)^T, bf16 in, f32/bf16 out ---
template<int BF16OUT>
__global__ __launch_bounds__(256, 2)
void gemm_bt(const unsigned short* __restrict__ A, const unsigned short* __restrict__ B,
             void* __restrict__ Cv, int K, int lda, int ldb, int ldc,
             long bsA, long bsB, long bsC)
{
  const int bz = blockIdx.z;
  A += (long)bz*bsA; B += (long)bz*bsB;
  const int m0 = blockIdx.x<<7, n0 = blockIdx.y<<7;
  __shared__ __align__(16) unsigned short lA[128*32];
  __shared__ __align__(16) unsigned short lB[128*32];
  const int tid = threadIdx.x, l = tid&63, w = tid>>6;
  const int li = l&15, g = l>>4;
  const int wm = (w>>1)<<6, wn = (w&1)<<6;
  const int r0 = (l>>2), ce = (l&3)<<3;
  f32x4 acc[4][4];
  #pragma unroll
  for (int a_=0;a_<4;a_++)
    #pragma unroll
    for (int b_=0;b_<4;b_++) acc[a_][b_] = f32x4{0.f,0.f,0.f,0.f};

  for (int k0 = 0; k0 < K; k0 += 32){
    __syncthreads();
    #pragma unroll
    for (int i=0;i<2;i++){
      const int ch = (i<<2) + w;
      const int r  = (ch<<4) + r0;
      gll16(A + (long)(m0+r)*lda + k0 + ce, (char*)lA + (ch<<10));
      gll16(B + (long)(n0+r)*ldb + k0 + ce, (char*)lB + (ch<<10));
    }
    __syncthreads();
    bf16x8 af[4], bfv[4];
    #pragma unroll
    for (int mf=0;mf<4;mf++)
      af[mf] = *(const bf16x8*)((const char*)lA + (wm + (mf<<4) + li)*64 + (g<<4));
    #pragma unroll
    for (int nf=0;nf<4;nf++)
      bfv[nf] = *(const bf16x8*)((const char*)lB + (wn + (nf<<4) + li)*64 + (g<<4));
    #pragma unroll
    for (int mf=0;mf<4;mf++)
      #pragma unroll
      for (int nf=0;nf<4;nf++)
        acc[mf][nf] = MFMA(af[mf], bfv[nf], acc[mf][nf]);
  }
  #pragma unroll
  for (int mf=0;mf<4;mf++)
    #pragma unroll
    for (int nf=0;nf<4;nf++)
      #pragma unroll
      for (int j=0;j<4;j++){
        const int row = m0 + wm + (mf<<4) + (g<<2) + j;
        const int col = n0 + wn + (nf<<4) + li;
        if (BF16OUT)
          ((unsigned short*)Cv)[(long)bz*bsC + (long)row*ldc + col] = f2bf(acc[mf][nf][j]);
        else
          ((float*)Cv)[(long)bz*bsC + (long)row*ldc + col] = acc[mf][nf][j];
      }
}

// ---------------- flash attention (MLA absorbed; QK-dim 576, V-dim 512) -----
// v3: KVBLK=64; K double-buffered in LDS (all 512 threads stage, 9x gll16);
// V read directly from L2/L1 (vt layout, 64B-contiguous segments) - no V LDS;
// P per-wave LDS buffer reused for the two k=32 PV phases.
// 8 waves = 2 heads x 4 row-groups; chevron pairs (pi, 31-pi) -> 33 steps/block.
#define SCALE_F 0.07216878364870322f

__global__ __launch_bounds__(512, 2)
void attn(const unsigned short* __restrict__ qk,   // (B*S,16,576) bf16
          const unsigned short* __restrict__ kvc,  // (B*S,576)   bf16
          const unsigned short* __restrict__ vt,   // (B,512,2048) bf16
          unsigned short* __restrict__ o)          // (B*S,16,512) bf16
{
  const int pi = blockIdx.x, hp = blockIdx.y, b = blockIdx.z;
  const int tid = threadIdx.x, l = tid & 63, w = tid >> 6;
  const int li = l & 15, g = l >> 4;
  const int h  = (hp << 1) + (w >> 2);
  const int rg = w & 3;

  __shared__ __align__(16) unsigned short Kl[2][64*576];   // 2 x 72 KB
  __shared__ __align__(16) unsigned short Pl[8][16*40];    // 10 KB
  unsigned short* Pw = &Pl[w][0];

  // K staging: 64 rows x 72 chunks(16B) = 4608 chunks, 512 threads x 9.
  // XOR-swizzle chunk within row: slot c holds global chunk c^(r&7) (rule #21).
  int soff[9];
  #pragma unroll
  for (int i = 0; i < 9; i++){
    int ch = i*512 + tid;
    int r  = ch / 72;
    int c  = ch - r*72;
    int cs = c ^ (r & 7);
    soff[i] = r*576 + (cs << 3);    // in shorts
  }
  const unsigned short* sbase = kvc + (long)(b << 11)*576;
  const unsigned short* vbase = vt  + (long)(b << 9)*2048;

  auto STAGE = [&](int buf, int kt){
    const unsigned short* s = sbase + (long)(kt << 6)*576;
    char* d = (char*)&Kl[buf][0] + tid*16;
    #pragma unroll
    for (int i = 0; i < 9; i++) gll16(s + soff[i], d + i*8192);
  };

  #pragma unroll 1
  for (int half = 0; half < 2; half++){
    const int qt = half ? (31 - pi) : pi;
    const int q0 = (qt << 6) + (rg << 4);
    const int nsteps = qt + 1;

    // Q fragments (row q0+li of head h), 72 VGPRs
    bf16x8 qf[18];
    {
      const unsigned short* qp = qk + ((long)((b<<11) + q0 + li)*16 + h)*576 + (g<<3);
      #pragma unroll
      for (int ks = 0; ks < 18; ks++) qf[ks] = *(const bf16x8*)(qp + ks*32);
    }
    asm volatile("s_waitcnt vmcnt(0)" ::: "memory");   // clean slate for counted waits
    __builtin_amdgcn_sched_barrier(0);

    f32x4 accO[32];
    #pragma unroll
    for (int i = 0; i < 32; i++) accO[i] = f32x4{0.f,0.f,0.f,0.f};
    float mrow[4] = {-1e30f,-1e30f,-1e30f,-1e30f};
    float lrow[4] = {0.f,0.f,0.f,0.f};

    STAGE(0, 0);
    int cur = 0;

    #pragma unroll 1
    for (int kt = 0; kt < nsteps; kt++){
      const int tn = (kt + 1 < nsteps) ? kt + 1 : kt;
      STAGE(cur ^ 1, tn);
      asm volatile("s_waitcnt vmcnt(9)" ::: "memory");
      __builtin_amdgcn_sched_barrier(0);
      __builtin_amdgcn_s_barrier();               // K[cur] ready everywhere

      const int t0 = kt << 6;
      const char* Kb = (const char*)&Kl[cur][0];

      // QK^T : 16 q-rows x 64 t  (72 MFMAs)
      f32x4 sc[4];
      sc[0] = f32x4{0.f,0.f,0.f,0.f}; sc[1] = sc[0]; sc[2] = sc[0]; sc[3] = sc[0];
      #pragma unroll
      for (int ks = 0; ks < 18; ks++){
        const int cb = (ks<<6) + (g<<4);
        #pragma unroll
        for (int n = 0; n < 4; n++){
          const int tt = (n<<4) + li;
          bf16x8 kf = *(const bf16x8*)(Kb + tt*1152 + (cb ^ ((tt&7)<<4)));
          sc[n] = MFMA(qf[ks], kf, sc[n]);
        }
      }

      // online softmax (rows g*4+j, cols t0 + n*16 + li)
      float corr[4];
      unsigned pp[2][4];                          // packed bf16 P pairs
      #pragma unroll
      for (int j = 0; j < 4; j++){
        const int q = q0 + (g<<2) + j;
        float s_[4];
        #pragma unroll
        for (int n = 0; n < 4; n++){
          s_[n] = sc[n][j]*SCALE_F;
          if (t0 + (n<<4) + li > q) s_[n] = -1e30f;
        }
        float mx = fmaxf(fmaxf(s_[0], s_[1]), fmaxf(s_[2], s_[3]));
        #pragma unroll
        for (int d = 1; d < 16; d <<= 1) mx = fmaxf(mx, __shfl_xor(mx, d, 64));
        const float mnew = fmaxf(mrow[j], mx);
        corr[j] = __expf(mrow[j] - mnew);
        mrow[j] = mnew;
        float p0 = __expf(s_[0] - mnew);
        float p1 = __expf(s_[1] - mnew);
        float p2 = __expf(s_[2] - mnew);
        float p3 = __expf(s_[3] - mnew);
        float rs = (p0 + p1) + (p2 + p3);
        #pragma unroll
        for (int d = 1; d < 16; d <<= 1) rs += __shfl_xor(rs, d, 64);
        lrow[j] = lrow[j]*corr[j] + rs;
        pp[0][j] = (unsigned)f2bf(p0) | ((unsigned)f2bf(p1) << 16);
        pp[1][j] = (unsigned)f2bf(p2) | ((unsigned)f2bf(p3) << 16);
      }
      #pragma unroll
      for (int nf = 0; nf < 32; nf++){
        f32x4 a = accO[nf];
        a[0]*=corr[0]; a[1]*=corr[1]; a[2]*=corr[2]; a[3]*=corr[3];
        accO[nf] = a;
      }

      // PV in two k=32 phases; V B-frags straight from L1/L2 (vt rows, 64B seg)
      #pragma unroll
      for (int kh = 0; kh < 2; kh++){
        #pragma unroll
        for (int j = 0; j < 4; j++){
          Pw[((g<<2)+j)*40 + li]      = (unsigned short)(pp[kh][j] & 0xffffu);
          Pw[((g<<2)+j)*40 + 16 + li] = (unsigned short)(pp[kh][j] >> 16);
        }
        asm volatile("s_waitcnt lgkmcnt(0)" ::: "memory");  // P landed (wave-local)
        __builtin_amdgcn_sched_barrier(0);
        const bf16x8 pa = *(const bf16x8*)((const char*)Pw + li*80 + (g<<4));
        const unsigned short* vrow = vbase + t0 + (kh<<5) + (g<<3);
        #pragma unroll 4
        for (int nf = 0; nf < 32; nf++){
          const int c = (nf<<4) + li;
          bf16x8 vb = *(const bf16x8*)(vrow + (long)c*2048);
          accO[nf] = MFMA(pa, vb, accO[nf]);
        }
        if (kh == 0){
          asm volatile("s_waitcnt lgkmcnt(0)" ::: "memory"); // P reads done before rewrite
          __builtin_amdgcn_sched_barrier(0);
        }
      }
      __builtin_amdgcn_sched_barrier(0);
      __builtin_amdgcn_s_barrier();               // all K[cur] reads done
      cur ^= 1;
    }

    // epilogue: O write
    #pragma unroll
    for (int j = 0; j < 4; j++){
      const float inv = 1.0f/lrow[j];
      const int q = q0 + (g<<2) + j;
      unsigned short* op = o + ((long)((b<<11) + q)*16 + h)*512 + li;
      #pragma unroll
      for (int nf = 0; nf < 32; nf++) op[nf<<4] = f2bf(accO[nf][j]*inv);
    }
  }
}

// ---------------- host ----------------

extern "C" void kernel_launch(void* const* d_in, const int* in_sizes, int n_in,
                              void* d_out, int out_size, void* d_ws, size_t ws_size,
                              hipStream_t stream)
{
  const float* x    = (const float*)d_in[0];
  const float* wq   = (const float*)d_in[1];
  const float* wkva = (const float*)d_in[2];
  const float* kvw  = (const float*)d_in[3];
  const float* wkvb = (const float*)d_in[4];
  const float* wo   = (const float*)d_in[5];
  const float* fc   = (const float*)d_in[6];
  const float* fs   = (const float*)d_in[7];
  float* out = (float*)d_out;

  char* ws = (char*)d_ws;
  auto alloc = [&](size_t bytes)->void*{
    void* p = ws; ws += (bytes + 255) & ~(size_t)255; return p;
  };
  unsigned short* x_bf    = (unsigned short*)alloc( 8388608ull*2);  // (4096,2048)
  unsigned short* wq_bf   = (unsigned short*)alloc( 6291456ull*2);  // (3072,2048)
  unsigned short* wkva_p  = (unsigned short*)alloc( 1310720ull*2);  // (640,2048)
  unsigned short* wkvb_bf = (unsigned short*)alloc( 2097152ull*2);  // (4096,512)
  unsigned short* wbkT    = (unsigned short*)alloc( 1048576ull*2);  // (16,512,128)
  unsigned short* wo_bf   = (unsigned short*)alloc( 4194304ull*2);  // (2048,2048)
  unsigned short* q_bf    = (unsigned short*)alloc(12582912ull*2);  // (4096,3072)
  unsigned short* kv_bf   = (unsigned short*)alloc( 2621440ull*2);  // (4096,640)
  unsigned short* qkcat   = (unsigned short*)alloc(37748736ull*2);  // (4096,16,576)
  unsigned short* kvcat   = (unsigned short*)alloc( 2359296ull*2);  // (4096,576)
  unsigned short* vtb     = (unsigned short*)alloc( 2097152ull*2);  // (2,512,2048)
  unsigned short* obuf    = (unsigned short*)alloc(33554432ull*2);  // (4096,16,512)
  unsigned short* o2      = (unsigned short*)alloc( 8388608ull*2);  // (4096,2048)

  k_f2b <<<8192,256,0,stream>>>(x,    x_bf,    8388608);
  k_f2b <<<6144,256,0,stream>>>(wq,   wq_bf,   6291456);
  k_wkva<<<1280,256,0,stream>>>(wkva, wkva_p);
  k_f2b <<<2048,256,0,stream>>>(wkvb, wkvb_bf, 2097152);
  k_wbkT<<<4096,256,0,stream>>>(wkvb, wbkT);
  k_f2b <<<4096,256,0,stream>>>(wo,   wo_bf,   4194304);

  // q = x @ wq^T   (4096,3072)
  gemm_bt<1><<<dim3(32,24,1),256,0,stream>>>(x_bf, wq_bf, q_bf, 2048, 2048, 2048, 3072, 0,0,0);
  // kv = x @ wkv_a^T (padded N=640)
  gemm_bt<1><<<dim3(32,5,1),256,0,stream>>>(x_bf, wkva_p, kv_bf, 2048, 2048, 2048, 640, 0,0,0);

  k_ropeq <<<8192,256,0,stream>>>(q_bf, fc, fs, qkcat);
  k_kvnorm<<<1024,256,0,stream>>>(kv_bf, kvw, kvcat);
  k_ropek <<<512, 256,0,stream>>>(kv_bf, fc, fs, kvcat);

  // q_proj[h] = q_nope[h] @ wbk[h]^T -> qkcat cols 0..511
  gemm_bt<1><<<dim3(32,4,16),256,0,stream>>>(q_bf, wbkT, qkcat, 128, 3072, 128, 9216,
                                             192, 65536, 576);
  k_vt<<<8192,256,0,stream>>>(kvcat, vtb);

  attn<<<dim3(16,8,2),512,0,stream>>>(qkcat, kvcat, vtb, obuf);

  // o2[h] = o[h] @ wv[h]^T  (wv rows = wkv_b rows h*256+128..255, native layout)
  gemm_bt<1><<<dim3(32,1,16),256,0,stream>>>(obuf, wkvb_bf + 65536, o2, 512, 8192, 512, 2048,
                                             512, 131072, 128);
  // out = o2 @ wo^T  (f32)
  gemm_bt<0><<<dim3(32,16,1),256,0,stream>>>(o2, wo_bf, out, 2048, 2048, 2048, 2048, 0,0,0);
}

// Round 8
// 698.258 us; speedup vs baseline: 3.7501x; 3.7501x over previous
//
#include <hip/hip_runtime.h>

#define DI __device__ __forceinline__

typedef __bf16 bf16x8 __attribute__((ext_vector_type(8)));
typedef float  f32x4  __attribute__((ext_vector_type(4)));

DI unsigned short f2bf(float f){
  unsigned u = __builtin_bit_cast(unsigned, f);
  u = (u + 0x7fffu + ((u >> 16) & 1u)) >> 16;   // RNE
  return (unsigned short)u;
}
DI float b2f(unsigned short h){
  return __builtin_bit_cast(float, (unsigned)h << 16);
}
DI f32x4 MFMA(bf16x8 a, bf16x8 b, f32x4 c){
  return __builtin_amdgcn_mfma_f32_16x16x32_bf16(a, b, c, 0, 0, 0);
}
DI void gll16(const void* g, void* l){
  __builtin_amdgcn_global_load_lds((const __attribute__((address_space(1))) void*)g,
                                   (__attribute__((address_space(3))) void*)l,
                                   16, 0, 0);
}

// ---------------- elementwise / prep kernels ----------------

__global__ void k_f2b(const float* __restrict__ in, unsigned short* __restrict__ out, long n){
  long i = ((long)blockIdx.x*256 + threadIdx.x)*4;
  if (i >= n) return;
  float4 v = *(const float4*)(in + i);
  ushort4 r; r.x=f2bf(v.x); r.y=f2bf(v.y); r.z=f2bf(v.z); r.w=f2bf(v.w);
  *(ushort4*)(out + i) = r;
}

// wkv_a (576,2048) f32 -> (640,2048) bf16, pad rows zero
__global__ void k_wkva(const float* __restrict__ in, unsigned short* __restrict__ out){
  int idx = blockIdx.x*256 + threadIdx.x;         // 1280*256 = 640*2048/4
  long i = (long)idx*4;
  int row = (int)(i >> 11), col = (int)(i & 2047);
  ushort4 r;
  if (row < 576){
    float4 v = *(const float4*)(in + (long)row*2048 + col);
    r.x=f2bf(v.x); r.y=f2bf(v.y); r.z=f2bf(v.z); r.w=f2bf(v.w);
  } else { r.x=0; r.y=0; r.z=0; r.w=0; }
  *(ushort4*)(out + i) = r;
}

// wbkT[h][c][d] = wkv_b[(h*256 + d)*512 + c], d<128   (16,512,128) bf16
__global__ void k_wbkT(const float* __restrict__ wkvb, unsigned short* __restrict__ out){
  int i = blockIdx.x*256 + threadIdx.x;           // 4096*256 = 16*512*128
  int d = i & 127, c = (i>>7)&511, h = i>>16;
  out[i] = f2bf(wkvb[(long)((h<<8) + d)*512 + c]);
}

// rope q_pe: q_bf (4096,3072) -> qkcat cols 512..575
__global__ void k_ropeq(const unsigned short* __restrict__ q, const float* __restrict__ fc,
                        const float* __restrict__ fs, unsigned short* __restrict__ qkcat){
  int i = blockIdx.x*256 + threadIdx.x;           // 8192*256 = 4096*16*32
  int p = i & 31, h = (i>>5)&15, m = i>>9;
  int s = m & 2047;
  const unsigned short* qp = q + (long)m*3072 + h*192 + 128 + (p<<1);
  float xr = b2f(qp[0]), xi = b2f(qp[1]);
  float c = fc[(s<<5)+p], sn = fs[(s<<5)+p];
  unsigned short* dst = qkcat + ((long)m*16 + h)*576 + 512 + (p<<1);
  dst[0] = f2bf(xr*c - xi*sn);
  dst[1] = f2bf(xr*sn + xi*c);
}

// rope k_pe: kv_bf (4096,640) cols 512..575 -> kvcat cols 512..575
__global__ void k_ropek(const unsigned short* __restrict__ kv, const float* __restrict__ fc,
                        const float* __restrict__ fs, unsigned short* __restrict__ kvcat){
  int i = blockIdx.x*256 + threadIdx.x;           // 512*256 = 4096*32
  int p = i & 31, m = i>>5;
  int s = m & 2047;
  const unsigned short* kp = kv + (long)m*640 + 512 + (p<<1);
  float xr = b2f(kp[0]), xi = b2f(kp[1]);
  float c = fc[(s<<5)+p], sn = fs[(s<<5)+p];
  unsigned short* dst = kvcat + (long)m*576 + 512 + (p<<1);
  dst[0] = f2bf(xr*c - xi*sn);
  dst[1] = f2bf(xr*sn + xi*c);
}

// RMSNorm kv_c rows of 512 -> kvcat cols 0..511 (one wave per row)
__global__ __launch_bounds__(256)
void k_kvnorm(const unsigned short* __restrict__ kv, const float* __restrict__ w,
              unsigned short* __restrict__ kvcat){
  int m = blockIdx.x*4 + (threadIdx.x>>6);
  int l = threadIdx.x & 63;
  const unsigned short* row = kv + (long)m*640 + (l<<3);
  float v[8]; float ss = 0.f;
  #pragma unroll
  for (int j=0;j<8;j++){ v[j] = b2f(row[j]); ss += v[j]*v[j]; }
  #pragma unroll
  for (int d=1; d<64; d<<=1) ss += __shfl_xor(ss, d, 64);
  float r = rsqrtf(ss*(1.f/512.f) + 1.1920929e-07f);
  unsigned short* dst = kvcat + (long)m*576 + (l<<3);
  const float* wp = w + (l<<3);
  #pragma unroll
  for (int j=0;j<8;j++) dst[j] = f2bf(v[j]*r*wp[j]);
}

// vt[b][c][t] = kvcat[(b*2048+t)*576 + c]   (2,512,2048) bf16
__global__ void k_vt(const unsigned short* __restrict__ kvcat, unsigned short* __restrict__ vt){
  int i = blockIdx.x*256 + threadIdx.x;           // 8192*256 = 2*512*2048
  int t = i & 2047, c = (i>>11)&511, b = i>>20;
  vt[i] = kvcat[(long)((b<<11)+t)*576 + c];
}

// ---------------- GEMM: C(MxN) = A(MxK) * B(NxK)^T, bf16 in, f32/bf16 out ---
template<int BF16OUT>
__global__ __launch_bounds__(256, 2)
void gemm_bt(const unsigned short* __restrict__ A, const unsigned short* __restrict__ B,
             void* __restrict__ Cv, int K, int lda, int ldb, int ldc,
             long bsA, long bsB, long bsC)
{
  const int bz = blockIdx.z;
  A += (long)bz*bsA; B += (long)bz*bsB;
  const int m0 = blockIdx.x<<7, n0 = blockIdx.y<<7;
  __shared__ __align__(16) unsigned short lA[128*32];
  __shared__ __align__(16) unsigned short lB[128*32];
  const int tid = threadIdx.x, l = tid&63, w = tid>>6;
  const int li = l&15, g = l>>4;
  const int wm = (w>>1)<<6, wn = (w&1)<<6;
  const int r0 = (l>>2), ce = (l&3)<<3;
  f32x4 acc[4][4];
  #pragma unroll
  for (int a_=0;a_<4;a_++)
    #pragma unroll
    for (int b_=0;b_<4;b_++) acc[a_][b_] = f32x4{0.f,0.f,0.f,0.f};

  for (int k0 = 0; k0 < K; k0 += 32){
    __syncthreads();
    #pragma unroll
    for (int i=0;i<2;i++){
      const int ch = (i<<2) + w;
      const int r  = (ch<<4) + r0;
      gll16(A + (long)(m0+r)*lda + k0 + ce, (char*)lA + (ch<<10));
      gll16(B + (long)(n0+r)*ldb + k0 + ce, (char*)lB + (ch<<10));
    }
    __syncthreads();
    bf16x8 af[4], bfv[4];
    #pragma unroll
    for (int mf=0;mf<4;mf++)
      af[mf] = *(const bf16x8*)((const char*)lA + (wm + (mf<<4) + li)*64 + (g<<4));
    #pragma unroll
    for (int nf=0;nf<4;nf++)
      bfv[nf] = *(const bf16x8*)((const char*)lB + (wn + (nf<<4) + li)*64 + (g<<4));
    #pragma unroll
    for (int mf=0;mf<4;mf++)
      #pragma unroll
      for (int nf=0;nf<4;nf++)
        acc[mf][nf] = MFMA(af[mf], bfv[nf], acc[mf][nf]);
  }
  #pragma unroll
  for (int mf=0;mf<4;mf++)
    #pragma unroll
    for (int nf=0;nf<4;nf++)
      #pragma unroll
      for (int j=0;j<4;j++){
        const int row = m0 + wm + (mf<<4) + (g<<2) + j;
        const int col = n0 + wn + (nf<<4) + li;
        if (BF16OUT)
          ((unsigned short*)Cv)[(long)bz*bsC + (long)row*ldc + col] = f2bf(acc[mf][nf][j]);
        else
          ((float*)Cv)[(long)bz*bsC + (long)row*ldc + col] = acc[mf][nf][j];
      }
}

// ---------------- flash attention (MLA absorbed; QK-dim 576, V-dim 512) -----
// Round-5 structure (KVBLK=32, K+V double-buffered LDS, proven 467us) +
// defer-max softmax (T13) + per-lane partial row-sums + setprio around MFMA.
// 8 waves = 2 heads x 4 row-groups; chevron pairs (pi,31-pi) -> 68 steps/block.
#define SCALE_F 0.07216878364870322f

__global__ __launch_bounds__(512, 2)
void attn(const unsigned short* __restrict__ qk,   // (B*S,16,576) bf16
          const unsigned short* __restrict__ kvc,  // (B*S,576)   bf16
          const unsigned short* __restrict__ vt,   // (B,512,2048) bf16
          unsigned short* __restrict__ o)          // (B*S,16,512) bf16
{
  const int pi = blockIdx.x, hp = blockIdx.y, b = blockIdx.z;
  const int tid = threadIdx.x, l = tid & 63, w = tid >> 6;
  const int li = l & 15, g = l >> 4;
  const int h  = (hp << 1) + (w >> 2);
  const int rg = w & 3;

  __shared__ __align__(16) unsigned short Kl[2][32*576];   // 2 x 36 KB
  __shared__ __align__(16) unsigned short Vl[2][512*32];   // 2 x 32 KB
  __shared__ __align__(16) unsigned short Pl[8][16*40];    // 10 KB
  unsigned short* Pw = &Pl[w][0];

  // precomputed staging source offsets (t0-independent part)
  int soff[9];
  const unsigned short* sbase;
  if (w < 4){
    sbase = kvc + (long)(b << 11) * 576;
    #pragma unroll
    for (int i = 0; i < 9; i++){
      int ch = i*256 + tid;
      int r  = ch / 72;
      int cb = (ch - r*72) << 4;
      int cbs = cb ^ ((r & 7) << 4);      // pre-swizzled source (rule #21)
      soff[i] = r*576 + (cbs >> 1);
    }
  } else {
    sbase = vt + (long)(b << 9) * 2048;
    #pragma unroll
    for (int i = 0; i < 8; i++){
      int ch = i*256 + (tid - 256);
      int c  = ch >> 2;
      int tb = (ch & 3) << 4;
      int tbs = tb ^ ((c & 3) << 4);
      soff[i] = c*2048 + (tbs >> 1);
    }
    soff[8] = 0;
  }

  auto STAGE = [&](int buf, int kt){
    const int t0 = kt << 5;
    if (w < 4){
      const unsigned short* s = sbase + (long)t0 * 576;
      char* d = (char*)&Kl[buf][0] + tid*16;
      #pragma unroll
      for (int i = 0; i < 9; i++) gll16(s + soff[i], d + i*4096);
    } else {
      const unsigned short* s = sbase + t0;
      char* d = (char*)&Vl[buf][0] + (tid - 256)*16;
      #pragma unroll
      for (int i = 0; i < 8; i++) gll16(s + soff[i], d + i*4096);
    }
  };

  #pragma unroll 1
  for (int half = 0; half < 2; half++){
    const int qt = half ? (31 - pi) : pi;
    const int q0 = (qt << 6) + (rg << 4);
    const int nsteps = (qt << 1) + 2;

    // Q fragments for this tile (row q0+li of head h)
    bf16x8 qf[18];
    {
      const unsigned short* qp = qk + ((long)((b<<11) + q0 + li)*16 + h)*576 + (g<<3);
      #pragma unroll
      for (int ks = 0; ks < 18; ks++) qf[ks] = *(const bf16x8*)(qp + ks*32);
    }
    asm volatile("s_waitcnt vmcnt(0)" ::: "memory");   // clean slate for counted waits
    __builtin_amdgcn_sched_barrier(0);

    f32x4 accO[32];
    #pragma unroll
    for (int i = 0; i < 32; i++) accO[i] = f32x4{0.f,0.f,0.f,0.f};
    float mrow[4] = {-1e30f,-1e30f,-1e30f,-1e30f};
    float lsum[4] = {0.f,0.f,0.f,0.f};

    STAGE(0, 0);
    int cur = 0;

    #pragma unroll 1
    for (int kt = 0; kt < nsteps; kt++){
      const int tn = (kt + 1 < nsteps) ? kt + 1 : kt;
      STAGE(cur ^ 1, tn);
      if (w < 4) asm volatile("s_waitcnt vmcnt(9)" ::: "memory");
      else       asm volatile("s_waitcnt vmcnt(8)" ::: "memory");
      __builtin_amdgcn_sched_barrier(0);
      __builtin_amdgcn_s_barrier();               // cur buffers ready everywhere

      const int t0 = kt << 5;
      const char* Kb = (const char*)&Kl[cur][0];
      const char* Vb = (const char*)&Vl[cur][0];
      // QK^T : 16 q-rows x 32 t
      f32x4 sc0 = f32x4{0.f,0.f,0.f,0.f}, sc1 = f32x4{0.f,0.f,0.f,0.f};
      const int swz = (li & 7) << 4;
      __builtin_amdgcn_s_setprio(1);
      #pragma unroll
      for (int ks = 0; ks < 18; ks++){
        const int cb = ((ks<<6) + (g<<4)) ^ swz;
        bf16x8 k0 = *(const bf16x8*)(Kb + li*1152 + cb);
        bf16x8 k1 = *(const bf16x8*)(Kb + (16+li)*1152 + cb);
        sc0 = MFMA(qf[ks], k0, sc0);
        sc1 = MFMA(qf[ks], k1, sc1);
      }
      __builtin_amdgcn_s_setprio(0);

      // defer-max online softmax (T13): stale max + per-lane partial sums;
      // full reduce + rescale only when some score exceeds mrow+8.
      float s0v[4], s1v[4];
      #pragma unroll
      for (int j = 0; j < 4; j++){
        const int q = q0 + (g<<2) + j;
        s0v[j] = sc0[j]*SCALE_F;
        s1v[j] = sc1[j]*SCALE_F;
        if (t0 + li      > q) s0v[j] = -1e30f;
        if (t0 + 16 + li > q) s1v[j] = -1e30f;
      }
      bool viol = false;
      #pragma unroll
      for (int j = 0; j < 4; j++)
        viol = viol || (fmaxf(s0v[j], s1v[j]) > mrow[j] + 8.0f);
      if (__any(viol)){
        float cr[4];
        #pragma unroll
        for (int j = 0; j < 4; j++){
          float mx = fmaxf(s0v[j], s1v[j]);
          #pragma unroll
          for (int d = 1; d < 16; d <<= 1) mx = fmaxf(mx, __shfl_xor(mx, d, 64));
          const float mnew = fmaxf(mrow[j], mx);
          cr[j] = __expf(mrow[j] - mnew);
          mrow[j] = mnew;
          lsum[j] *= cr[j];
        }
        #pragma unroll
        for (int nf = 0; nf < 32; nf++){
          f32x4 a = accO[nf];
          a[0]*=cr[0]; a[1]*=cr[1]; a[2]*=cr[2]; a[3]*=cr[3];
          accO[nf] = a;
        }
      }
      #pragma unroll
      for (int j = 0; j < 4; j++){
        const float p0 = __expf(s0v[j] - mrow[j]);
        const float p1 = __expf(s1v[j] - mrow[j]);
        lsum[j] += p0 + p1;
        Pw[((g<<2)+j)*40 + li]      = f2bf(p0);
        Pw[((g<<2)+j)*40 + 16 + li] = f2bf(p1);
      }
      asm volatile("s_waitcnt lgkmcnt(0)" ::: "memory");  // P writes landed (wave-local)
      __builtin_amdgcn_sched_barrier(0);
      const bf16x8 pa = *(const bf16x8*)((const char*)Pw + li*80 + (g<<4));
      __builtin_amdgcn_s_setprio(1);
      #pragma unroll
      for (int nf = 0; nf < 32; nf++){
        const int c = (nf<<4) + li;
        bf16x8 vb = *(const bf16x8*)(Vb + c*64 + ((g<<4) ^ ((c&3)<<4)));
        accO[nf] = MFMA(pa, vb, accO[nf]);
      }
      __builtin_amdgcn_s_setprio(0);
      __builtin_amdgcn_sched_barrier(0);
      __builtin_amdgcn_s_barrier();               // all reads of cur done -> next STAGE may overwrite
      cur ^= 1;
    }

    // epilogue: reduce per-lane partial sums within 16-lane group, write O
    #pragma unroll
    for (int j = 0; j < 4; j++){
      float ls = lsum[j];
      #pragma unroll
      for (int d = 1; d < 16; d <<= 1) ls += __shfl_xor(ls, d, 64);
      const float inv = 1.0f/ls;
      const int q = q0 + (g<<2) + j;
      unsigned short* op = o + ((long)((b<<11) + q)*16 + h)*512 + li;
      #pragma unroll
      for (int nf = 0; nf < 32; nf++) op[nf<<4] = f2bf(accO[nf][j]*inv);
    }
  }
}

// ---------------- host ----------------

extern "C" void kernel_launch(void* const* d_in, const int* in_sizes, int n_in,
                              void* d_out, int out_size, void* d_ws, size_t ws_size,
                              hipStream_t stream)
{
  const float* x    = (const float*)d_in[0];
  const float* wq   = (const float*)d_in[1];
  const float* wkva = (const float*)d_in[2];
  const float* kvw  = (const float*)d_in[3];
  const float* wkvb = (const float*)d_in[4];
  const float* wo   = (const float*)d_in[5];
  const float* fc   = (const float*)d_in[6];
  const float* fs   = (const float*)d_in[7];
  float* out = (float*)d_out;

  char* ws = (char*)d_ws;
  auto alloc = [&](size_t bytes)->void*{
    void* p = ws; ws += (bytes + 255) & ~(size_t)255; return p;
  };
  unsigned short* x_bf    = (unsigned short*)alloc( 8388608ull*2);  // (4096,2048)
  unsigned short* wq_bf   = (unsigned short*)alloc( 6291456ull*2);  // (3072,2048)
  unsigned short* wkva_p  = (unsigned short*)alloc( 1310720ull*2);  // (640,2048)
  unsigned short* wkvb_bf = (unsigned short*)alloc( 2097152ull*2);  // (4096,512)
  unsigned short* wbkT    = (unsigned short*)alloc( 1048576ull*2);  // (16,512,128)
  unsigned short* wo_bf   = (unsigned short*)alloc( 4194304ull*2);  // (2048,2048)
  unsigned short* q_bf    = (unsigned short*)alloc(12582912ull*2);  // (4096,3072)
  unsigned short* kv_bf   = (unsigned short*)alloc( 2621440ull*2);  // (4096,640)
  unsigned short* qkcat   = (unsigned short*)alloc(37748736ull*2);  // (4096,16,576)
  unsigned short* kvcat   = (unsigned short*)alloc( 2359296ull*2);  // (4096,576)
  unsigned short* vtb     = (unsigned short*)alloc( 2097152ull*2);  // (2,512,2048)
  unsigned short* obuf    = (unsigned short*)alloc(33554432ull*2);  // (4096,16,512)
  unsigned short* o2      = (unsigned short*)alloc( 8388608ull*2);  // (4096,2048)

  k_f2b <<<8192,256,0,stream>>>(x,    x_bf,    8388608);
  k_f2b <<<6144,256,0,stream>>>(wq,   wq_bf,   6291456);
  k_wkva<<<1280,256,0,stream>>>(wkva, wkva_p);
  k_f2b <<<2048,256,0,stream>>>(wkvb, wkvb_bf, 2097152);
  k_wbkT<<<4096,256,0,stream>>>(wkvb, wbkT);
  k_f2b <<<4096,256,0,stream>>>(wo,   wo_bf,   4194304);

  // q = x @ wq^T   (4096,3072)
  gemm_bt<1><<<dim3(32,24,1),256,0,stream>>>(x_bf, wq_bf, q_bf, 2048, 2048, 2048, 3072, 0,0,0);
  // kv = x @ wkv_a^T (padded N=640)
  gemm_bt<1><<<dim3(32,5,1),256,0,stream>>>(x_bf, wkva_p, kv_bf, 2048, 2048, 2048, 640, 0,0,0);

  k_ropeq <<<8192,256,0,stream>>>(q_bf, fc, fs, qkcat);
  k_kvnorm<<<1024,256,0,stream>>>(kv_bf, kvw, kvcat);
  k_ropek <<<512, 256,0,stream>>>(kv_bf, fc, fs, kvcat);

  // q_proj[h] = q_nope[h] @ wbk[h]^T -> qkcat cols 0..511
  gemm_bt<1><<<dim3(32,4,16),256,0,stream>>>(q_bf, wbkT, qkcat, 128, 3072, 128, 9216,
                                             192, 65536, 576);
  k_vt<<<8192,256,0,stream>>>(kvcat, vtb);

  attn<<<dim3(16,8,2),512,0,stream>>>(qkcat, kvcat, vtb, obuf);

  // o2[h] = o[h] @ wv[h]^T  (wv rows = wkv_b rows h*256+128..255, native layout)
  gemm_bt<1><<<dim3(32,1,16),256,0,stream>>>(obuf, wkvb_bf + 65536, o2, 512, 8192, 512, 2048,
                                             512, 131072, 128);
  // out = o2 @ wo^T  (f32)
  gemm_bt<0><<<dim3(32,16,1),256,0,stream>>>(o2, wo_bf, out, 2048, 2048, 2048, 2048, 0,0,0);
}